// Round 2
// baseline (16349.487 us; speedup 1.0000x reference)
//
#include <hip/hip_runtime.h>
#include <math.h>

#define NB 8
#define HH 52
#define WW 52
#define LL 2704
#define CC 256
#define HC 26
#define WC 26
#define SS 676
#define C2 512
#define FCn 8
#define SCn 32
#define M16 (NB*LL)     // 21632
#define M32 (NB*SS)     // 5408
#define KCONV (9*C2)    // 4608

__device__ __forceinline__ float  gelu_ct(float x){ return 0.5f*x*(1.0f + erff(x*0.70710678118654752f)); }
__device__ __forceinline__ double gelu_ct(double x){ return 0.5*x*(1.0 + erf(x*0.70710678118654752440)); }

// ---------------- generic tiled GEMM, compute type CT: Out = [gelu](cat(A0,A1) @ W + bias)
// A0: (M,K0) row-major, A1: (M,K-K0) row-major (if CAT), W: (K,N) f32 row-major.
template<typename CT, typename TA0, typename TA1, typename TO, bool GELU, bool CAT>
__global__ __launch_bounds__(256) void gemm_t(
    const TA0* __restrict__ A0, const TA1* __restrict__ A1, int K0,
    const float* __restrict__ W, const float* __restrict__ Bias,
    TO* __restrict__ Out, int M, int K, int N)
{
    __shared__ CT As[16][65];
    __shared__ CT Bs[16][65];
    const int t = threadIdx.x;
    const int tm = t & 15, tn = t >> 4;
    const int mBase = blockIdx.x * 64;
    const int nBase = blockIdx.y * 64;
    const int arow = t >> 2;          // 0..63
    const int kof  = (t & 3) << 2;    // 0,4,8,12
    const int brow = t >> 4;          // 0..15
    const int nof  = (t & 15) << 2;   // 0..60
    CT acc[4][4] = {};
    const int am = mBase + arow;
    for (int k0 = 0; k0 < K; k0 += 16){
        CT a[4] = {CT(0),CT(0),CT(0),CT(0)};
        if (am < M){
            #pragma unroll
            for (int j=0;j<4;j++){
                int k = k0 + kof + j;
                if (!CAT || k < K0) a[j] = (CT)A0[(size_t)am*K0 + k];
                else                a[j] = (CT)A1[(size_t)am*(K-K0) + (k-K0)];
            }
        }
        CT b[4];
        #pragma unroll
        for (int j=0;j<4;j++)
            b[j] = (CT)W[(size_t)(k0+brow)*N + nBase + nof + j];
        __syncthreads();
        #pragma unroll
        for (int j=0;j<4;j++) As[kof+j][arow] = a[j];
        #pragma unroll
        for (int j=0;j<4;j++) Bs[brow][nof+j] = b[j];
        __syncthreads();
        #pragma unroll
        for (int kk=0;kk<16;kk++){
            CT av[4], bv[4];
            #pragma unroll
            for (int i=0;i<4;i++) av[i] = As[kk][(tm<<2)+i];
            #pragma unroll
            for (int j=0;j<4;j++) bv[j] = Bs[kk][(tn<<2)+j];
            #pragma unroll
            for (int i=0;i<4;i++)
                #pragma unroll
                for (int j=0;j<4;j++)
                    acc[i][j] += av[i]*bv[j];
        }
    }
    const int n0 = nBase + (tn<<2);
    #pragma unroll
    for (int i=0;i<4;i++){
        int m = mBase + (tm<<2) + i;
        if (m < M){
            #pragma unroll
            for (int j=0;j<4;j++){
                CT v = acc[i][j] + (CT)Bias[n0+j];
                if (GELU) v = gelu_ct(v);
                Out[(size_t)m*N + n0 + j] = (TO)v;
            }
        }
    }
}

// ---------------- 3x3 conv as implicit GEMM (f32): X (M16,512) NHWC, WT (4608,256) ------
__global__ __launch_bounds__(256) void conv_k(const float* __restrict__ X,
    const float* __restrict__ WT, const float* __restrict__ Bias, float* __restrict__ Out)
{
    __shared__ float As[16][64];
    __shared__ float Bs[16][64];
    const int t = threadIdx.x;
    const int tm = t & 15, tn = t >> 4;
    const int mBase = blockIdx.x * 64;
    const int oBase = blockIdx.y * 64;
    const int prow = t >> 2;
    const int kof  = (t & 3) << 2;
    const int nof  = (t & 15) << 2;
    float acc[4][4] = {};
    const int am = mBase + prow;
    const int an = am / LL; const int ahw = am % LL;
    const int ah = ahw / WW; const int aw = ahw % WW;
    for (int kh = 0; kh < 3; kh++){
        const int h2 = ah + kh - 1;
        for (int kw = 0; kw < 3; kw++){
            const int w2 = aw + kw - 1;
            const bool ok = (h2 >= 0 && h2 < HH && w2 >= 0 && w2 < WW);
            const int hcl = min(max(h2,0), HH-1);
            const int wcl = min(max(w2,0), WW-1);
            const float* ap = X + ((size_t)(an*LL + hcl*WW + wcl))*C2;
            const float* wp = WT + (size_t)((kh*3+kw)*C2)*CC + oBase;
            for (int i0 = 0; i0 < C2; i0 += 16){
                float4 a = ok ? *(const float4*)(ap + i0 + kof) : make_float4(0.f,0.f,0.f,0.f);
                float4 b = *(const float4*)(wp + (size_t)(i0 + tn)*CC + nof);
                __syncthreads();
                As[kof+0][prow] = a.x; As[kof+1][prow] = a.y;
                As[kof+2][prow] = a.z; As[kof+3][prow] = a.w;
                *(float4*)&Bs[tn][nof] = b;
                __syncthreads();
                #pragma unroll
                for (int kk = 0; kk < 16; kk++){
                    float4 av = *(const float4*)&As[kk][tm<<2];
                    float4 bv = *(const float4*)&Bs[kk][tn<<2];
                    float aa[4] = {av.x, av.y, av.z, av.w};
                    float bbv[4] = {bv.x, bv.y, bv.z, bv.w};
                    #pragma unroll
                    for (int i=0;i<4;i++)
                        #pragma unroll
                        for (int j=0;j<4;j++)
                            acc[i][j] += aa[i]*bbv[j];
                }
            }
        }
    }
    const int o0 = oBase + (tn<<2);
    float4 b4 = *(const float4*)(Bias + o0);
    float bb[4] = {b4.x, b4.y, b4.z, b4.w};
    #pragma unroll
    for (int i=0;i<4;i++){
        int m = mBase + (tm<<2) + i;
        float o[4];
        #pragma unroll
        for (int j=0;j<4;j++) o[j] = acc[i][j] + bb[j];
        *(float4*)(Out + (size_t)m*CC + o0) = make_float4(o[0],o[1],o[2],o[3]);
    }
}

// ---------------- conv weight transpose: (O,I,3,3) -> (k = khw*512+i, o) ----------------
__global__ void wtrans_k(const float* __restrict__ wsrc, float* __restrict__ wt){
    int o = threadIdx.x;
    int k = blockIdx.x;
    int khkw = k / C2; int i = k % C2;
    wt[(size_t)k*CC + o] = wsrc[((size_t)o*C2 + i)*9 + khkw];
}

// ---------------- bilinear upsample 26x26 -> 52x52 for ONE sample, f64 out --------------
__global__ void ups_k(const float* __restrict__ cen, double* __restrict__ up){
    int idx = blockIdx.x*256 + threadIdx.x;     // < 2704*256
    int c = idx & 255;
    int l = idx >> 8;
    int h = l / WW, w = l % WW;
    double fy = (h==HH-1) ? (double)(HC-1) : h*((double)(HC-1)/(HH-1));
    double fx = (w==WW-1) ? (double)(WC-1) : w*((double)(WC-1)/(WW-1));
    int y0 = (int)fy; int y1 = min(y0+1, HC-1);
    int x0 = (int)fx; int x1 = min(x0+1, WC-1);
    double dy = fy - y0, dx = fx - x0;
    const float* base = cen + c;
    double v00 = (double)base[(size_t)(y0*WC + x0)*CC];
    double v01 = (double)base[(size_t)(y0*WC + x1)*CC];
    double v10 = (double)base[(size_t)(y1*WC + x0)*CC];
    double v11 = (double)base[(size_t)(y1*WC + x1)*CC];
    double r0 = v00*(1.0-dy) + v10*dy;
    double r1 = v01*(1.0-dy) + v11*dy;
    up[idx] = r0*(1.0-dx) + r1*dx;
}

// ---------------- per-sample GroupNorm stats (f64 sum, sumsq) ---------------------------
__global__ __launch_bounds__(256) void gn_stats_k(const double* __restrict__ t2c,
    double* __restrict__ stats, int n){
    int i0 = blockIdx.x*4096 + threadIdx.x;
    double s = 0.0, q = 0.0;
    #pragma unroll
    for (int r = 0; r < 16; r++){
        double v = t2c[i0 + r*256];
        s += v; q += v*v;
    }
    #pragma unroll
    for (int off = 32; off; off >>= 1){
        s += __shfl_xor(s, off);
        q += __shfl_xor(q, off);
    }
    __shared__ double ls[4], lq[4];
    int wid = threadIdx.x >> 6;
    if ((threadIdx.x & 63) == 0){ ls[wid] = s; lq[wid] = q; }
    __syncthreads();
    if (threadIdx.x == 0){
        atomicAdd(&stats[n*2+0], ls[0]+ls[1]+ls[2]+ls[3]);
        atomicAdd(&stats[n*2+1], lq[0]+lq[1]+lq[2]+lq[3]);
    }
}

// ---------------- mx(sample) = GN(t2c)+x, f64 out ---------------------------------------
__global__ void merge_x_k(const double* __restrict__ t2c, const float* __restrict__ x,
    const float* __restrict__ g, const float* __restrict__ b,
    const double* __restrict__ stats, int n, double* __restrict__ mxn){
    int idx = blockIdx.x*256 + threadIdx.x;
    const double inv = 1.0/((double)LL*CC);
    int c = idx & (CC-1);
    double mu = stats[2*n]*inv;
    double var = stats[2*n+1]*inv - mu*mu;
    double r = 1.0/sqrt(var + 1e-5);
    mxn[idx] = (t2c[idx]-mu)*r*(double)g[c] + (double)b[c] + (double)x[idx];
}

// ---------------- mc(sample) = down(GN(t2c)) + center, f64 out --------------------------
__global__ void merge_c_k(const double* __restrict__ t2c, const float* __restrict__ cen,
    const float* __restrict__ g, const float* __restrict__ b,
    const double* __restrict__ stats, int n, double* __restrict__ mcn){
    int idx = blockIdx.x*256 + threadIdx.x;     // < 676*256
    int c = idx & 255;
    int s = idx >> 8;
    int i = s / WC, j = s % WC;
    double fy = (i==WC-1) ? (double)(HH-1) : i*((double)(HH-1)/(HC-1));
    double fx = (j==WC-1) ? (double)(WW-1) : j*((double)(WW-1)/(WC-1));
    int y0 = (int)fy; int y1 = min(y0+1, HH-1);
    int x0 = (int)fx; int x1 = min(x0+1, WW-1);
    double dy = fy - y0, dx = fx - x0;
    const double* base = t2c + c;
    double v00 = base[(size_t)(y0*WW + x0)*CC];
    double v01 = base[(size_t)(y0*WW + x1)*CC];
    double v10 = base[(size_t)(y1*WW + x0)*CC];
    double v11 = base[(size_t)(y1*WW + x1)*CC];
    double r0 = v00*(1.0-dy) + v10*dy;
    double r1 = v01*(1.0-dy) + v11*dy;
    double v = r0*(1.0-dx) + r1*dx;
    const double inv = 1.0/((double)LL*CC);
    double mu = stats[2*n]*inv;
    double var = stats[2*n+1]*inv - mu*mu;
    double r = 1.0/sqrt(var + 1e-5);
    mcn[idx] = (v-mu)*r*(double)g[c] + (double)b[c] + (double)cen[idx];
}

// ---------------- normalize cpt -> ctn (n*8+h, s, 32), f64 ------------------------------
__global__ __launch_bounds__(256) void cptn_k(const double* __restrict__ cp, double* __restrict__ ctn){
    int ns = blockIdx.x;                 // 0..M32
    int n = ns / SS, s = ns % SS;
    int hgrp = threadIdx.x >> 5, k = threadIdx.x & 31;
    double v = cp[(size_t)ns*C2 + hgrp*64 + k];
    double q = v*v;
    #pragma unroll
    for (int off = 16; off; off >>= 1) q += __shfl_xor(q, off, 32);
    double d = fmax(sqrt(q), 1e-12);
    ctn[((size_t)(n*FCn + hgrp)*SS + s)*SCn + k] = v/d;
}

// ---------------- f64 cosine sim + sigmoid + argmax + gather, ONE sample ----------------
__global__ __launch_bounds__(256) void sim_k(const double* __restrict__ xpc,
    const double* __restrict__ ctn, const double* __restrict__ cp,
    const float* __restrict__ alpha_p, const float* __restrict__ beta_p,
    int n, float* __restrict__ disp)
{
    int l = blockIdx.x*256 + threadIdx.x;
    if (l >= LL) return;
    int h = blockIdx.y;
    double alpha = (double)alpha_p[0], beta = (double)beta_p[0];
    double xv[32];
    const double* xr = xpc + (size_t)l*CC + h*SCn;
    double sq = 0.0;
    #pragma unroll
    for (int k=0;k<32;k++){ xv[k] = xr[k]; sq += xv[k]*xv[k]; }
    double inv = 1.0 / fmax(sqrt(sq), 1e-12);
    #pragma unroll
    for (int k=0;k<32;k++) xv[k] *= inv;
    const double* cb = ctn + ((size_t)(n*FCn + h))*SS*SCn;
    double zbest = -1.0e300; int bi = 0;
    for (int s=0;s<SS;s++){
        const double* cr = cb + (size_t)s*SCn;
        double d = 0.0;
        #pragma unroll
        for (int k=0;k<32;k++) d += xv[k]*cr[k];
        double z = alpha*d + beta;
        if (z > zbest){ zbest = z; bi = s; }
    }
    double val;
    if (zbest >= 0.0) val = 1.0/(1.0 + exp(-zbest));
    else { double e = exp(zbest); val = e/(1.0+e); }
    const double* cv = cp + ((size_t)(n*SS + bi))*C2 + h*64 + 32;
    float* dr = disp + ((size_t)(n*LL + l))*CC + h*SCn;
    #pragma unroll
    for (int k=0;k<32;k++) dr[k] = (float)(val*cv[k]);
}

// ---------------- row LayerNorm in-place f32 (row = 256) --------------------------------
__global__ __launch_bounds__(256) void ln_rows_k(float* __restrict__ y,
    const float* __restrict__ g, const float* __restrict__ b){
    int row = blockIdx.x*4 + (threadIdx.x >> 6);
    int lane = threadIdx.x & 63;
    float* rp = y + (size_t)row*CC;
    float4 v = *(const float4*)(rp + lane*4);
    float s = v.x+v.y+v.z+v.w;
    float q = v.x*v.x+v.y*v.y+v.z*v.z+v.w*v.w;
    #pragma unroll
    for (int off = 32; off; off >>= 1){ s += __shfl_xor(s, off); q += __shfl_xor(q, off); }
    float mu = s*(1.0f/CC);
    float var = q*(1.0f/CC) - mu*mu;
    float r = rsqrtf(var + 1e-5f);
    int c = lane*4;
    float4 gv = *(const float4*)(g+c);
    float4 bv = *(const float4*)(b+c);
    float4 o;
    o.x = (v.x-mu)*r*gv.x+bv.x;
    o.y = (v.y-mu)*r*gv.y+bv.y;
    o.z = (v.z-mu)*r*gv.z+bv.z;
    o.w = (v.w-mu)*r*gv.w+bv.w;
    *(float4*)(rp+c) = o;
}

// ---------------- final: out = LN(out)*g+b + res(f64) -----------------------------------
__global__ __launch_bounds__(256) void final_k(float* __restrict__ y, const double* __restrict__ res,
    const float* __restrict__ g, const float* __restrict__ b){
    int row = blockIdx.x*4 + (threadIdx.x >> 6);
    int lane = threadIdx.x & 63;
    float* rp = y + (size_t)row*CC;
    const double* xp = res + (size_t)row*CC;
    float4 v = *(const float4*)(rp + lane*4);
    float s = v.x+v.y+v.z+v.w;
    float q = v.x*v.x+v.y*v.y+v.z*v.z+v.w*v.w;
    #pragma unroll
    for (int off = 32; off; off >>= 1){ s += __shfl_xor(s, off); q += __shfl_xor(q, off); }
    float mu = s*(1.0f/CC);
    float var = q*(1.0f/CC) - mu*mu;
    float r = rsqrtf(var + 1e-5f);
    int c = lane*4;
    float4 gv = *(const float4*)(g+c);
    float4 bv = *(const float4*)(b+c);
    float4 o;
    o.x = (v.x-mu)*r*gv.x+bv.x + (float)xp[c+0];
    o.y = (v.y-mu)*r*gv.y+bv.y + (float)xp[c+1];
    o.z = (v.z-mu)*r*gv.z+bv.z + (float)xp[c+2];
    o.w = (v.w-mu)*r*gv.w+bv.w + (float)xp[c+3];
    *(float4*)(rp+c) = o;
}

extern "C" void kernel_launch(void* const* d_in, const int* in_sizes, int n_in,
                              void* d_out, int out_size, void* d_ws, size_t ws_size,
                              hipStream_t stream)
{
    const float* x16[2] = {(const float*)d_in[0], (const float*)d_in[1]};
    const float* x32[2] = {(const float*)d_in[2], (const float*)d_in[3]};
    const float* mb_l0_w = (const float*)d_in[6];
    const float* mb_l0_b = (const float*)d_in[7];
    const float* mb_l1_w = (const float*)d_in[8];
    const float* mb_l1_b = (const float*)d_in[9];
    const float* mb_gn_g = (const float*)d_in[10];
    const float* mb_gn_b = (const float*)d_in[11];
    const float* gc_p0_w = (const float*)d_in[12];
    const float* gc_p0_b = (const float*)d_in[13];
    const float* gc_p1_w = (const float*)d_in[14];
    const float* gc_p1_b = (const float*)d_in[15];
    const float* gc_m_w  = (const float*)d_in[16];
    const float* gc_m_b  = (const float*)d_in[17];
    const float* gc_alpha= (const float*)d_in[18];
    const float* gc_beta = (const float*)d_in[19];
    const float* gb_n0_g = (const float*)d_in[20];
    const float* gb_n0_b = (const float*)d_in[21];
    const float* gb_lin_w= (const float*)d_in[22];
    const float* gb_lin_b= (const float*)d_in[23];
    const float* gb_conv_w=(const float*)d_in[24];
    const float* gb_conv_b=(const float*)d_in[25];
    const float* gb_n1_g = (const float*)d_in[26];
    const float* gb_n1_b = (const float*)d_in[27];

    // ---------------- workspace layout (bytes) ----------------
    const size_t F8  = (size_t)M16*CC*8;      // 44,302,336
    const size_t G8  = (size_t)M32*CC*8;      // 11,075,584
    const size_t WT4 = (size_t)KCONV*CC*4;    //  4,718,592
    const size_t SAMP16 = (size_t)LL*CC;      // elems per sample, 16x
    const size_t SAMP32 = (size_t)SS*CC;      // elems per sample, 32x

    char* base = (char*)d_ws;
    double* mx[2] = { (double*)base, (double*)(base + F8) };
    double* mc[2] = { (double*)(base + 2*F8), (double*)(base + 2*F8 + G8) };
    char*   pWT   = base + 2*F8 + 2*G8;
    float*  WT    = (float*)pWT;
    double* stats = (double*)(pWT + WT4);
    char*   E     = pWT + WT4 + 256;

    // merge-phase scratch (per sample)
    double* t2c = (double*)E;                              //  5,537,792 B
    double* t1c = (double*)(E + 5537792);                  // 11,075,584 B
    double* upc = (double*)(E + 16613376);                 //  5,537,792 B
    // global-phase scratch
    double* cp   = (double*)E;                             // 22,151,168 B
    double* ctn  = (double*)(E + 22151168);                // 11,075,584 B
    double* xpc  = (double*)(E + 33226752);                //  5,537,792 B
    float*  disp = (float*) (E + 38764544);                // 22,151,168 B
    float*  Dbuf = (float*) E;                             // 22,151,168 B (over cp, after sim)
    float*  Bbuf = (float*) (E + 22151168);                // 44,302,336 B (over ctn.., after Dbuf)

    const size_t need = 2*F8 + 2*G8 + WT4 + 256 + 66453504;
    if (ws_size < need) return;

    wtrans_k<<<KCONV, 256, 0, stream>>>(gb_conv_w, WT);

    // -------- merge blocks (f64, per sample) --------
    for (int i = 0; i < 2; i++){
        for (int n = 0; n < NB; n++){
            ups_k<<<LL, 256, 0, stream>>>(x32[i] + (size_t)n*SAMP32, upc);
            gemm_t<double,float,double,double,true,true><<<dim3(43, 8), 256, 0, stream>>>(
                x16[i] + (size_t)n*SAMP16, upc, CC, mb_l0_w, mb_l0_b, t1c, LL, C2, C2);
            gemm_t<double,double,double,double,false,false><<<dim3(43, 4), 256, 0, stream>>>(
                t1c, (const double*)nullptr, C2, mb_l1_w, mb_l1_b, t2c, LL, C2, CC);
            hipMemsetAsync((char*)stats + n*16, 0, 16, stream);
            gn_stats_k<<<169, 256, 0, stream>>>(t2c, stats, n);
            merge_x_k<<<LL, 256, 0, stream>>>(t2c, x16[i] + (size_t)n*SAMP16,
                mb_gn_g, mb_gn_b, stats, n, mx[i] + (size_t)n*SAMP16);
            merge_c_k<<<SS, 256, 0, stream>>>(t2c, x32[i] + (size_t)n*SAMP32,
                mb_gn_g, mb_gn_b, stats, n, mc[i] + (size_t)n*SAMP32);
        }
    }

    // -------- global blocks (f64 pre-sim, f32 post-sim) --------
    float* outp[2] = { (float*)d_out, (float*)d_out + (size_t)M16*CC };
    for (int i = 0; i < 2; i++){
        const double* xi64 = mx[i];
        const double* ci64 = mc[1-i];
        gemm_t<double,double,double,double,false,false><<<dim3(85, 8), 256, 0, stream>>>(
            ci64, (const double*)nullptr, CC, gc_p1_w, gc_p1_b, cp, M32, CC, C2);
        cptn_k<<<M32, 256, 0, stream>>>(cp, ctn);
        for (int n = 0; n < NB; n++){
            gemm_t<double,double,double,double,false,false><<<dim3(43, 4), 256, 0, stream>>>(
                xi64 + (size_t)n*SAMP16, (const double*)nullptr, CC, gc_p0_w, gc_p0_b,
                xpc, LL, CC, CC);
            sim_k<<<dim3(11, FCn), 256, 0, stream>>>(xpc, ctn, cp, gc_alpha, gc_beta, n, disp);
        }
        gemm_t<float,float,float,float,false,false><<<dim3(338, 4), 256, 0, stream>>>(
            disp, (const float*)nullptr, CC, gc_m_w, gc_m_b, Dbuf, M16, CC, CC);
        ln_rows_k<<<M16/4, 256, 0, stream>>>(Dbuf, gb_n0_g, gb_n0_b);
        gemm_t<float,double,float,float,true,true><<<dim3(338, 8), 256, 0, stream>>>(
            xi64, Dbuf, CC, gb_lin_w, gb_lin_b, Bbuf, M16, C2, C2);
        conv_k<<<dim3(338, 4), 256, 0, stream>>>(Bbuf, WT, gb_conv_b, outp[i]);
        final_k<<<M16/4, 256, 0, stream>>>(outp[i], xi64, gb_n1_g, gb_n1_b);
    }
}